// Round 8
// baseline (399.877 us; speedup 1.0000x reference)
//
#include <hip/hip_runtime.h>
#include <stdint.h>

typedef __bf16 bf16;
typedef __bf16 bf16x8 __attribute__((ext_vector_type(8)));
typedef __bf16 bf16x4 __attribute__((ext_vector_type(4)));
typedef float  f32x4  __attribute__((ext_vector_type(4)));

#define NB   4096   // sequence length
#define DB   1024   // model dim
#define RV   64     // low rank
#define MB   16384  // B*N
#define NSEG 8      // lowrank split-n factor

// ---- dtype detection (verified working, rounds 4-5) ----
__global__ void detect_dtype(const unsigned short* x, int* flag) {
  __shared__ int cnt;
  if (threadIdx.x == 0) cnt = 0;
  __syncthreads();
  int local = 0;
  for (int i = threadIdx.x; i < 8192; i += 256) {
    const int e = (x[i] >> 7) & 0xFF;
    if (e >= 0xC0) local++;
  }
  atomicAdd(&cnt, local);
  __syncthreads();
  if (threadIdx.x == 0) *flag = (cnt > 64) ? 1 : 0;  // 1 => inputs are f32
}

// ---- one dispatch converts the 6 big input tensors (E/F handled by ef_transpose) ----
struct CvtArgs {
  const void* src[8];
  bf16* dst[8];
  int n[8];
  int off[9];   // block-range prefix sums
};
__global__ void to_bf16_multi(CvtArgs a, const int* __restrict__ flag) {
  const int blk = blockIdx.x;
  int seg = 0;
#pragma unroll
  for (int s = 1; s < 8; ++s) seg += (blk >= a.off[s]);
  const int i = (blk - a.off[seg]) * 2048 + threadIdx.x * 8;
  if (i >= a.n[seg]) return;
  bf16* dst = a.dst[seg];
  if (*flag) {
    const float* s = (const float*)a.src[seg] + i;
    f32x4 x0 = *(const f32x4*)s;
    f32x4 x1 = *(const f32x4*)(s + 4);
    bf16x8 v;
    v[0]=(bf16)x0[0]; v[1]=(bf16)x0[1]; v[2]=(bf16)x0[2]; v[3]=(bf16)x0[3];
    v[4]=(bf16)x1[0]; v[5]=(bf16)x1[1]; v[6]=(bf16)x1[2]; v[7]=(bf16)x1[3];
    *(bf16x8*)(dst + i) = v;
  } else {
    *(uint4*)(dst + i) = *(const uint4*)((const bf16*)a.src[seg] + i);
  }
}

// EFt[m][n] = (m<64 ? E : F)[n][m&63]  -- 128x4096 bf16, built once (1 MB).
__global__ __launch_bounds__(256) void ef_transpose(
    const void* __restrict__ E, const void* __restrict__ F,
    bf16* __restrict__ EFt, const int* __restrict__ flag) {
  const int m = blockIdx.x;           // 0..127
  const int z = m >> 6, r = m & 63;
  const void* src = z ? F : E;
  const int t = threadIdx.x;
  bf16* dst = EFt + (size_t)m * 4096;
  if (*flag) {
    const float* s = (const float*)src;
#pragma unroll
    for (int i = 0; i < 16; ++i) {
      const int n = i*256 + t;
      dst[n] = (bf16)s[(size_t)n*RV + r];
    }
  } else {
    const bf16* s = (const bf16*)src;
#pragma unroll
    for (int i = 0; i < 16; ++i) {
      const int n = i*256 + t;
      dst[n] = s[(size_t)n*RV + r];
    }
  }
}

// async global->LDS, 16B per lane, wave-uniform LDS base
typedef __attribute__((address_space(1))) const void g_as1_void;
typedef __attribute__((address_space(3))) void as3_void;
static __device__ __forceinline__ void gload16(const void* g, void* l) {
  __builtin_amdgcn_global_load_lds((g_as1_void*)g, (as3_void*)l, 16, 0, 0);
}

// Partial xE/xF via MFMA, split-n: block (b, dt, seg) contracts n-rows
// [seg*512, seg*512+512) and writes f32 partials Pf[seg][b][128][1024].
__global__ __launch_bounds__(256, 4) void lowrank_mfma(
    const bf16* __restrict__ EFt, const bf16* __restrict__ xb,
    float* __restrict__ Pf) {
  const int b = blockIdx.x, dt = blockIdx.y, seg = blockIdx.z;
  __shared__ __align__(16) bf16 sEF0[128*64];   // 16 KiB
  __shared__ __align__(16) bf16 sEF1[128*64];   // 16 KiB
  __shared__ __align__(16) bf16 sXT[32*64];     // 4 KiB  [d][k] swizzled
  const int t = threadIdx.x, lane = t & 63, w = t >> 6;
  const int lr = lane & 15, quad = lane >> 4;
  const int wm = (w & 1) * 64, wd = (w >> 1) * 16;
  const int nbase = seg * (NB / NSEG);          // 512 rows per segment

  const bf16* gA[4];
  int abase[4];                      // wave-uniform LDS base (elements)
#pragma unroll
  for (int i = 0; i < 4; ++i) {
    const int c = i*256 + t, row = c >> 3, ch = c & 7;
    gA[i] = EFt + (size_t)row*4096 + nbase + (ch ^ (row & 7))*8;
    abase[i] = (i*256 + (w << 6)) * 8;
  }
  const bf16* gx = xb + ((size_t)b*NB + nbase + lane)*DB + dt*32 + w*8;
  int xslot[8];
#pragma unroll
  for (int j = 0; j < 8; ++j) {
    const int d = w*8 + j;
    xslot[j] = (d*8 + ((lane >> 3) ^ (d & 7)))*8 + (lane & 7);
  }
  f32x4 acc[4] = {};

  uint4 rx = *(const uint4*)gx;
#pragma unroll
  for (int i = 0; i < 4; ++i) gload16(gA[i], sEF0 + abase[i]);
  asm volatile("s_waitcnt vmcnt(0)" ::: "memory");
  __syncthreads();

  for (int kt = 0; kt < NB/NSEG; kt += 64) {
    {
      const bf16* px = (const bf16*)&rx;
#pragma unroll
      for (int j = 0; j < 8; ++j) sXT[xslot[j]] = px[j];
    }
    bf16* nbuf = ((kt >> 6) & 1) ? sEF0 : sEF1;   // buffer for kt+64
    if (kt + 64 < NB/NSEG) {
#pragma unroll
      for (int i = 0; i < 4; ++i) gload16(gA[i] + kt + 64, nbuf + abase[i]);
      rx = *(const uint4*)(gx + (size_t)(kt + 64)*DB);
    }
    asm volatile("s_waitcnt lgkmcnt(0)" ::: "memory");
    __syncthreads();
    const bf16* cbuf = ((kt >> 6) & 1) ? sEF1 : sEF0;
#pragma unroll
    for (int ks = 0; ks < 2; ++ks) {
      const int kc = ks*4 + quad;
      const int dd = wd + lr;
      bf16x8 bv = *(const bf16x8*)(sXT + (dd*8 + (kc ^ (dd & 7)))*8);
#pragma unroll
      for (int mi = 0; mi < 4; ++mi) {
        const int m = wm + mi*16 + lr;
        bf16x8 af = *(const bf16x8*)(cbuf + (m*8 + (kc ^ (m & 7)))*8);
        acc[mi] = __builtin_amdgcn_mfma_f32_16x16x32_bf16(af, bv, acc[mi], 0, 0, 0);
      }
    }
    if (kt + 64 < NB/NSEG) asm volatile("s_waitcnt vmcnt(1)" ::: "memory");
    __syncthreads();
  }

  // write f32 partials: Pf[(seg*4+b)][row128][d]
  float* dst = Pf + (((size_t)seg*4 + b)*128)*DB + dt*32 + wd + lr;
#pragma unroll
  for (int mi = 0; mi < 4; ++mi) {
    const int row128 = wm + mi*16 + quad*4;
#pragma unroll
    for (int rg = 0; rg < 4; ++rg)
      dst[(size_t)(row128 + rg)*DB] = acc[mi][rg];
  }
}

// xEb/xFb = bf16( sum_seg Pf[seg] )   (131072 threads, f32x4 loads)
__global__ __launch_bounds__(256) void lowrank_reduce(
    const float* __restrict__ Pf, bf16* __restrict__ xEb, bf16* __restrict__ xFb) {
  const int idx = blockIdx.x*256 + threadIdx.x;   // 0..131071
  const int d4  = idx & 255;          // d/4  (1024/4)
  const int row = (idx >> 8) & 127;   // 0..127
  const int b   = idx >> 15;          // 0..3
  const float* p = Pf + ((size_t)b*128 + row)*DB + d4*4;
  f32x4 s = {};
#pragma unroll
  for (int seg = 0; seg < NSEG; ++seg) {
    f32x4 v = *(const f32x4*)(p + (size_t)seg*4*128*DB);
    s[0]+=v[0]; s[1]+=v[1]; s[2]+=v[2]; s[3]+=v[3];
  }
  bf16x4 o;
  o[0]=(bf16)s[0]; o[1]=(bf16)s[1]; o[2]=(bf16)s[2]; o[3]=(bf16)s[3];
  bf16* dst = (row < 64 ? xEb : xFb) + ((size_t)b*64 + (row & 63))*DB + d4*4;
  *(bf16x4*)dst = o;
}

struct GemmArgs {
  const bf16* A;
  const bf16* B;
  void* C;
  const bf16* bias;
  const int* oflag;    // runtime f32-out flag (nullable)
  int force_f32;
  int M, N, K;
  const bf16* A2;      // dual mode: second GEMM on blockIdx.z==1
  const bf16* B2;
  void* C2;
  int dual;
  const float* Klow;   // fused-attention mode (Q-GEMM)
  const float* Vlow;
  int fuse_attn;
};

// C[m,n] = sum_k A[m,k]*B[n,k] (+bias[n]); fp32 accum.
// m97-structure: 128x128 tile, BK=64, 256 threads (4 waves, 2m x 2n),
// 32 KiB single-buffer LDS, plain drain loop; inter-block TLP (4 blocks/CU)
// provides the overlap (round-7: 47us, verified).
// fuse_attn: instead of writing Q, each wave's 64x64 quadrant (= 64 rows x
// one full head) runs attention in-epilogue: acc -> per-wave 8KiB LDS patch
// (A-layout bf16), S = Q.Klow^T (r=64 in-reg), row-softmax, O = P.Vlow with
// V gathered from L2-resident Vlow, write AO. Saves the whole attn kernel
// (67 MB traffic + launch). Layouts copied verbatim from verified attn_mfma.
// REQUIRES: M%128==0, N%128==0, K%64==0 (true for all launches here).
__global__ __launch_bounds__(256, 4) void gemm_nt(GemmArgs args) {
  const int K = args.K, N = args.N;
  const bf16* Aptr = args.A;
  const bf16* Bptr = args.B;
  void* Cptr = args.C;
  if (args.dual && blockIdx.z == 1) { Aptr = args.A2; Bptr = args.B2; Cptr = args.C2; }
  __shared__ __align__(16) char smem[32768];
  bf16* const sA = (bf16*)smem;
  bf16* const sB = (bf16*)(smem + 16384);

  const int t = threadIdx.x;
  const int lane = t & 63;
  const int w = t >> 6;
  const int lr = lane & 15;
  const int quad = lane >> 4;
  const int wm = (w & 1) * 64;     // 0 or 64
  const int wn = (w >> 1) * 64;    // 0 or 64

  int bx = blockIdx.x, by = blockIdx.y;
  if (gridDim.y == 128) {          // big-GEMM remap: 1024 blocks, 8 XCDs
    const int l = by * 8 + bx;     // dispatch order (x fastest)
    const int xcd = l & 7, s = l >> 3;   // s in [0,128)
    by = xcd * 16 + (s >> 3);      // XCD-exclusive 16-m-tile slab
    bx = s & 7;                    // n-fastest within slab
  }
  const int m0 = by * 128;
  const int n0 = bx * 128;

  // staging: 4 gload16/thread/tensor per K-tile (128 rows x 8 chunks).
  const bf16* gA[4];
  const bf16* gB[4];
  int lds_off[4];                  // bf16 elements
#pragma unroll
  for (int i = 0; i < 4; ++i) {
    const int c = i*256 + t;
    const int row = c >> 3, ch = c & 7;
    const int sc = ch ^ (row & 7);
    gA[i] = Aptr + (size_t)(m0 + row)*K + sc*8;
    gB[i] = Bptr + (size_t)(n0 + row)*K + sc*8;
    lds_off[i] = (i*256 + w*64) * 8;
  }

  f32x4 acc[4][4] = {};

  for (int kt = 0; kt < K; kt += 64) {
    __syncthreads();               // prev tile's LDS reads done
#pragma unroll
    for (int i = 0; i < 4; ++i) gload16(gA[i] + kt, sA + lds_off[i]);
#pragma unroll
    for (int i = 0; i < 4; ++i) gload16(gB[i] + kt, sB + lds_off[i]);
    __syncthreads();               // compiler drains vmcnt before s_barrier
#pragma unroll
    for (int ks = 0; ks < 2; ++ks) {
      const int kc = ks*4 + quad;
      bf16x8 af[4], bv[4];
#pragma unroll
      for (int mi = 0; mi < 4; ++mi) {
        const int m = wm + mi*16 + lr;
        af[mi] = *(const bf16x8*)(sA + (m*8 + (kc ^ (m & 7)))*8);
      }
#pragma unroll
      for (int ni = 0; ni < 4; ++ni) {
        const int n = wn + ni*16 + lr;
        bv[ni] = *(const bf16x8*)(sB + (n*8 + (kc ^ (n & 7)))*8);
      }
#pragma unroll
      for (int mi = 0; mi < 4; ++mi)
#pragma unroll
        for (int ni = 0; ni < 4; ++ni)
          acc[mi][ni] = __builtin_amdgcn_mfma_f32_16x16x32_bf16(
              af[mi], bv[ni], acc[mi][ni], 0, 0, 0);
    }
  }

  __syncthreads();   // LDS reuse (epilogue patches / attn patches)

  if (args.fuse_attn) {
    // --- fused attention: wave quadrant = 64 rows x head h (64 dims) ---
    const int b = m0 >> 12;                 // batch (4096 rows each)
    const int h = (n0 + wn) >> 6;           // global head 0..15
    bf16* patch = (bf16*)(smem + w * 8192); // per-wave 64x64 bf16, swizzled

    // Q (acc, C-layout) -> patch (A-layout)
#pragma unroll
    for (int mi = 0; mi < 4; ++mi)
#pragma unroll
      for (int ni = 0; ni < 4; ++ni)
#pragma unroll
        for (int rg = 0; rg < 4; ++rg) {
          const int row = mi*16 + quad*4 + rg;
          const int col = ni*16 + lr;
          patch[row*64 + ((col >> 3) ^ (row & 7))*8 + (col & 7)] =
              (bf16)acc[mi][ni][rg];
        }

    // S = Q . Klow^T  (contraction over head dim d=64)
    const float* Kb = args.Klow + (size_t)(b*64)*DB + h*64;
    f32x4 accS[4][4] = {};
#pragma unroll
    for (int ks = 0; ks < 2; ++ks) {
      const int kc = ks*4 + quad;
      bf16x8 af[4], bv[4];
#pragma unroll
      for (int mi = 0; mi < 4; ++mi) {
        const int m = mi*16 + lr;
        af[mi] = *(const bf16x8*)(patch + (m*8 + (kc ^ (m & 7)))*8);
      }
#pragma unroll
      for (int ni = 0; ni < 4; ++ni) {
        const int r = ni*16 + lr;
        f32x4 k0 = *(const f32x4*)(Kb + (size_t)r*DB + kc*8);
        f32x4 k1 = *(const f32x4*)(Kb + (size_t)r*DB + kc*8 + 4);
        bf16x8 kv;
        kv[0]=(bf16)k0[0]; kv[1]=(bf16)k0[1]; kv[2]=(bf16)k0[2]; kv[3]=(bf16)k0[3];
        kv[4]=(bf16)k1[0]; kv[5]=(bf16)k1[1]; kv[6]=(bf16)k1[2]; kv[7]=(bf16)k1[3];
        bv[ni] = kv;
      }
#pragma unroll
      for (int mi = 0; mi < 4; ++mi)
#pragma unroll
        for (int ni = 0; ni < 4; ++ni)
          accS[mi][ni] = __builtin_amdgcn_mfma_f32_16x16x32_bf16(
              af[mi], bv[ni], accS[mi][ni], 0, 0, 0);
    }

    // row softmax over r=64 (C-layout: row=mi*16+quad*4+rg, col r=ni*16+lr)
    float inv_[4][4];
#pragma unroll
    for (int mi = 0; mi < 4; ++mi)
#pragma unroll
      for (int rg = 0; rg < 4; ++rg) {
        float mv = -3.0e38f;
#pragma unroll
        for (int ni = 0; ni < 4; ++ni) mv = fmaxf(mv, accS[mi][ni][rg]);
#pragma unroll
        for (int d = 1; d < 16; d <<= 1) mv = fmaxf(mv, __shfl_xor(mv, d));
        float sum = 0.0f;
#pragma unroll
        for (int ni = 0; ni < 4; ++ni) {
          const float p = __expf((accS[mi][ni][rg] - mv) * 0.125f);
          accS[mi][ni][rg] = p;
          sum += p;
        }
#pragma unroll
        for (int d = 1; d < 16; d <<= 1) sum += __shfl_xor(sum, d);
        inv_[mi][rg] = 1.0f / sum;    // applied at O-write (PV linear)
      }

    // P -> patch (overwrites Q; all Q ds_reads already consumed, same-wave
    // LDS ops are in-order)
    asm volatile("s_waitcnt lgkmcnt(0)" ::: "memory");
#pragma unroll
    for (int mi = 0; mi < 4; ++mi)
#pragma unroll
      for (int ni = 0; ni < 4; ++ni)
#pragma unroll
        for (int rg = 0; rg < 4; ++rg) {
          const int row = mi*16 + quad*4 + rg;
          const int col = ni*16 + lr;
          patch[row*64 + ((col >> 3) ^ (row & 7))*8 + (col & 7)] =
              (bf16)accS[mi][ni][rg];
        }

    // O = P . Vlow   (contraction over r; B[n=d][k=r] gathered from Vlow)
    const float* Vb = args.Vlow + (size_t)(b*64)*DB + h*64;
    f32x4 accO[4][4] = {};
#pragma unroll
    for (int ks = 0; ks < 2; ++ks) {
      const int kc = ks*4 + quad;
      bf16x8 ap[4], bvv[4];
#pragma unroll
      for (int mi = 0; mi < 4; ++mi) {
        const int m = mi*16 + lr;
        ap[mi] = *(const bf16x8*)(patch + (m*8 + (kc ^ (m & 7)))*8);
      }
#pragma unroll
      for (int di = 0; di < 4; ++di) {
        const int d = di*16 + lr;
        bf16x8 vv;
#pragma unroll
        for (int j = 0; j < 8; ++j)
          vv[j] = (bf16)Vb[(size_t)(kc*8 + j)*DB + d];
        bvv[di] = vv;
      }
#pragma unroll
      for (int mi = 0; mi < 4; ++mi)
#pragma unroll
        for (int di = 0; di < 4; ++di)
          accO[mi][di] = __builtin_amdgcn_mfma_f32_16x16x32_bf16(
              ap[mi], bvv[di], accO[mi][di], 0, 0, 0);
    }

    // O*inv -> patch, then coalesced 16-B stores to AO
    asm volatile("s_waitcnt lgkmcnt(0)" ::: "memory");
#pragma unroll
    for (int mi = 0; mi < 4; ++mi)
#pragma unroll
      for (int di = 0; di < 4; ++di)
#pragma unroll
        for (int rg = 0; rg < 4; ++rg) {
          const int row = mi*16 + quad*4 + rg;
          const int col = di*16 + lr;
          patch[row*64 + ((col >> 3) ^ (row & 7))*8 + (col & 7)] =
              (bf16)(accO[mi][di][rg] * inv_[mi][rg]);
        }
    asm volatile("s_waitcnt lgkmcnt(0)" ::: "memory");
#pragma unroll
    for (int i = 0; i < 8; ++i) {
      const int c = i*64 + lane;
      const int row = c >> 3, ch = c & 7;
      const bf16x8 v = *(const bf16x8*)(patch + row*64 + ((ch ^ (row & 7))*8));
      *(bf16x8*)((bf16*)Cptr + (size_t)(m0 + wm + row)*N + h*64 + ch*8) = v;
    }
    return;
  }

  // plain epilogue: per-wave 8 KiB LDS patch (32x64 f32), 16-B stores.
  const int f32out = args.force_f32 | (args.oflag ? *args.oflag : 0);
  float* sEw = (float*)(smem + w * 8192);
#pragma unroll
  for (int hh = 0; hh < 2; ++hh) {
    if (hh) asm volatile("s_waitcnt lgkmcnt(0)" ::: "memory");  // WAR vs hh=0 reads
#pragma unroll
    for (int mi2 = 0; mi2 < 2; ++mi2) {
      const int mi = hh*2 + mi2;
#pragma unroll
      for (int ni = 0; ni < 4; ++ni) {
        const int colg = n0 + wn + ni*16 + lr;
        const float bvv = args.bias ? (float)args.bias[colg] : 0.0f;
#pragma unroll
        for (int rg = 0; rg < 4; ++rg) {
          const int row = mi2*16 + quad*4 + rg;   // 0..31
          sEw[row*64 + ((ni*16 + lr) ^ ((row & 15)*4))] = acc[mi][ni][rg] + bvv;
        }
      }
    }
    asm volatile("s_waitcnt lgkmcnt(0)" ::: "memory");
#pragma unroll
    for (int i = 0; i < 4; ++i) {
      const int c = i*64 + lane;
      const int row = c >> 3, ch = c & 7;
      const int d0 = ch * 8;
      const int swz = (row & 15) * 4;
      f32x4 v0 = *(const f32x4*)(sEw + row*64 + (d0 ^ swz));
      f32x4 v1 = *(const f32x4*)(sEw + row*64 + ((d0 + 4) ^ swz));
      const size_t base = (size_t)(m0 + wm + hh*32 + row)*N + n0 + wn + d0;
      if (f32out) {
        *(f32x4*)((float*)Cptr + base)     = v0;
        *(f32x4*)((float*)Cptr + base + 4) = v1;
      } else {
        bf16x8 wv;
        wv[0]=(bf16)v0[0]; wv[1]=(bf16)v0[1]; wv[2]=(bf16)v0[2]; wv[3]=(bf16)v0[3];
        wv[4]=(bf16)v1[0]; wv[5]=(bf16)v1[1]; wv[6]=(bf16)v1[2]; wv[7]=(bf16)v1[3];
        *(bf16x8*)((bf16*)Cptr + base) = wv;
      }
    }
  }
}

extern "C" void kernel_launch(void* const* d_in, const int* in_sizes, int n_in,
                              void* d_out, int out_size, void* d_ws, size_t ws_size,
                              hipStream_t stream) {
  char* ws = (char*)d_ws;
  const size_t MiB = 1024*1024;
  int*   flag = (int*)ws;
  float* Klow = (float*)(ws + 1*MiB);
  float* Vlow = (float*)(ws + 2*MiB);
  bf16*  xEb  = (bf16*)(ws + 3*MiB);
  bf16*  xFb  = (bf16*)(ws + 3*MiB + 512*1024);
  bf16*  EFt  = (bf16*)(ws + 4*MiB);
  bf16*  Wqb  = (bf16*)(ws + 7*MiB);
  bf16*  Wkb  = (bf16*)(ws + 9*MiB);
  bf16*  Wvb  = (bf16*)(ws + 11*MiB);
  bf16*  Wob  = (bf16*)(ws + 13*MiB);
  bf16*  bob  = (bf16*)(ws + 15*MiB);
  bf16*  xb   = (bf16*)(ws + 20*MiB);
  bf16*  S0   = (bf16*)(ws + 52*MiB);
  // Pf (16 MiB) aliases S0's region: written by lowrank_mfma, consumed by
  // lowrank_reduce, both strictly before the fused Q-GEMM writes S0.
  float* Pf   = (float*)(ws + 52*MiB);

  detect_dtype<<<1, 256, 0, stream>>>((const unsigned short*)d_in[0], flag);

  ef_transpose<<<dim3(128), 256, 0, stream>>>(d_in[6], d_in[7], EFt, flag);

  CvtArgs ca;
  bf16* dsts[6] = {xb, Wqb, Wkb, Wvb, Wob, bob};
  int   ns[6]   = {16777216, 1048576, 1048576, 1048576, 1048576, 1024};
  int off = 0;
  for (int i = 0; i < 6; ++i) {
    ca.src[i] = d_in[i]; ca.dst[i] = dsts[i]; ca.n[i] = ns[i];
    ca.off[i] = off; off += (ns[i] + 2047) / 2048;
  }
  for (int i = 6; i < 8; ++i) {
    ca.src[i] = d_in[0]; ca.dst[i] = xb; ca.n[i] = 0; ca.off[i] = off;
  }
  ca.off[8] = off;
  to_bf16_multi<<<dim3(off), 256, 0, stream>>>(ca, flag);

  lowrank_mfma<<<dim3(4, 32, NSEG), 256, 0, stream>>>(EFt, xb, Pf);
  lowrank_reduce<<<dim3(512), 256, 0, stream>>>(Pf, xEb, xFb);

  GemmArgs ka;                       // dual: Klow = xE @ Wk^T ; Vlow = xF @ Wv^T
  ka.A = xEb; ka.B = Wkb; ka.C = Klow;
  ka.A2 = xFb; ka.B2 = Wvb; ka.C2 = Vlow;
  ka.dual = 1;
  ka.bias = nullptr; ka.oflag = nullptr; ka.force_f32 = 1;
  ka.M = 256; ka.N = DB; ka.K = DB;
  ka.Klow = nullptr; ka.Vlow = nullptr; ka.fuse_attn = 0;
  gemm_nt<<<dim3(8, 2, 2), 256, 0, stream>>>(ka);

  GemmArgs qa;                       // AO = attn(x @ Wq^T) fused
  qa.A = xb; qa.B = Wqb; qa.C = S0; qa.bias = nullptr;
  qa.oflag = nullptr; qa.force_f32 = 0;
  qa.A2 = nullptr; qa.B2 = nullptr; qa.C2 = nullptr; qa.dual = 0;
  qa.M = MB; qa.N = DB; qa.K = DB;
  qa.Klow = Klow; qa.Vlow = Vlow; qa.fuse_attn = 1;
  gemm_nt<<<dim3(8, 128, 1), 256, 0, stream>>>(qa);

  GemmArgs oa;                       // out = AO @ Wo^T + bo
  oa.A = S0; oa.B = Wob; oa.C = d_out; oa.bias = bob;
  oa.oflag = flag; oa.force_f32 = 0;
  oa.A2 = nullptr; oa.B2 = nullptr; oa.C2 = nullptr; oa.dual = 0;
  oa.M = MB; oa.N = DB; oa.K = DB;
  oa.Klow = nullptr; oa.Vlow = nullptr; oa.fuse_attn = 0;
  gemm_nt<<<dim3(8, 128, 1), 256, 0, stream>>>(oa);
}